// Round 13
// baseline (46.817 us; speedup 1.0000x reference)
//
#include <hip/hip_runtime.h>

namespace {
constexpr int kB   = 2;
constexpr int kC   = 64;
constexpr int kH   = 128;
constexpr int kW   = 240;
constexpr int kD0  = 16;          // disps 0,3,...,45
constexpr int kD1  = 5;           // disps -2,-1,0,1,2
constexpr int kWc1 = 285;
constexpr int kWc2 = 242;
constexpr int kPad = 48;          // left pad (>= max disp 45)
constexpr int kRow = 336;         // dwords per cpair row (48 pad |240 data |48 pad)
constexpr int kCP  = 32;          // channel pairs (64 channels)
constexpr int kGroups   = 3;      // cpair-parallel groups {11,11,10}
constexpr int kGThreads = 320;
constexpr int kThreads  = kGroups * kGThreads;  // 960 = 15 waves
constexpr int kRowsPerBlk = 4;    // VISIBILITY PROBE: 4 (b,h) rows per block
constexpr int kAcc  = kD0 + kD1;  // 21
constexpr int kRStr = kWc1 * kAcc;             // 5985 floats per partial slot
constexpr int kOut1 = kB * kD0 * kH * kWc1;
constexpr int kN1   = kD0 * kWc1;              // 4560
constexpr int kN2   = kD1 * kWc2;              // 1210
typedef unsigned int v2u __attribute__((ext_vector_type(2)));
typedef float v2f __attribute__((ext_vector_type(2)));

__device__ __forceinline__ v2f UP(unsigned int x) {   // bf16x2 -> {lo,hi} f32
  v2f f;
  f.x = __uint_as_float(x << 16);
  f.y = __uint_as_float(x & 0xffff0000u);
  return f;
}
__device__ __forceinline__ unsigned int pk2(float lo, float hi) {
  unsigned int r;
  asm("v_cvt_pk_bf16_f32 %0, %1, %2" : "=v"(r) : "v"(lo), "v"(hi));
  return r;
}
__device__ __forceinline__ v2f pfma(v2f a, v2f b, v2f c) {
  return __builtin_elementwise_fma(a, b, c);   // -> v_pk_fma_f32
}
}

__global__ __launch_bounds__(kThreads)
void anynet_disp_kernel(const float* __restrict__ fr, float* __restrict__ out) {
  __shared__ unsigned int E[kCP * kRow];  // bf16x2 exp(feat_r): ch 2cp | 2cp+1
  __shared__ float P[kGroups * kRStr];    // dedicated partial slots
  const int blk = blockIdx.x;             // 0..63
  const int tid = threadIdx.x;
  const int g = tid / kGThreads;          // 0..2
  const int t = tid % kGThreads;

  for (int rr = 0; rr < kRowsPerBlk; ++rr) {
    const int bh = blk * kRowsPerBlk + rr;   // 0..255
    const int b  = bh >> 7;
    const int h  = bh & 127;

    // ---- phase A (R9-identical per row): MLP loads + pads + exp/pack
    const float* fr_b = fr + (size_t)b * kC * kH * kW + (size_t)h * kW;
    const int i0 = tid, i1 = tid + kThreads;        // both < 1920
    const int cp0 = i0 / 60, xq0 = i0 % 60;
    const int cp1 = i1 / 60, xq1 = i1 % 60;
    const float4 a0 = *reinterpret_cast<const float4*>(
        fr_b + (size_t)(2 * cp0) * (kH * kW) + 4 * xq0);
    const float4 b0 = *reinterpret_cast<const float4*>(
        fr_b + (size_t)(2 * cp0 + 1) * (kH * kW) + 4 * xq0);
    const float4 a1 = *reinterpret_cast<const float4*>(
        fr_b + (size_t)(2 * cp1) * (kH * kW) + 4 * xq1);
    const float4 b1 = *reinterpret_cast<const float4*>(
        fr_b + (size_t)(2 * cp1 + 1) * (kH * kW) + 4 * xq1);
    if (tid < kCP * 24) {
      const int cp = tid / 24, q = tid % 24;
      const int j4 = (q < 12) ? q : q + 60;         // uint4 [0,12) and [72,84)
      const uint4 ones = {0x3F803F80u, 0x3F803F80u, 0x3F803F80u, 0x3F803F80u};
      *reinterpret_cast<uint4*>(&E[cp * kRow + 4 * j4]) = ones;
    }
    {
      uint4 w0;
      w0.x = pk2(__expf(a0.x), __expf(b0.x));
      w0.y = pk2(__expf(a0.y), __expf(b0.y));
      w0.z = pk2(__expf(a0.z), __expf(b0.z));
      w0.w = pk2(__expf(a0.w), __expf(b0.w));
      *reinterpret_cast<uint4*>(&E[cp0 * kRow + kPad + 4 * xq0]) = w0;
      uint4 w1;
      w1.x = pk2(__expf(a1.x), __expf(b1.x));
      w1.y = pk2(__expf(a1.y), __expf(b1.y));
      w1.z = pk2(__expf(a1.z), __expf(b1.z));
      w1.w = pk2(__expf(a1.w), __expf(b1.w));
      *reinterpret_cast<uint4*>(&E[cp1 * kRow + kPad + 4 * xq1]) = w1;
    }
    __syncthreads();

    // ---- phase B (R9-identical): 10x ds_read2_b32 per cpair, packed math
    v2f acc1[kD0] = {};
    v2f acc2[kD1] = {};
    if (t < kWc1) {
      const int cbeg = (g == 0) ? 0 : (g == 1 ? 11 : 22);
      const int clen = (g < 2) ? 11 : 10;
      unsigned int addr = (unsigned int)(uintptr_t)(const void*)&E[cbeg * kRow + t + 3];
      for (int cc = 0; cc < clen; ++cc) {
        v2u p0, p1, p2, p3, p4, p5, p6, p7, q0, q1;
        asm volatile(
            "ds_read2_b32 %0, %10 offset0:45 offset1:42\n\t"
            "ds_read2_b32 %1, %10 offset0:39 offset1:36\n\t"
            "ds_read2_b32 %2, %10 offset0:33 offset1:30\n\t"
            "ds_read2_b32 %3, %10 offset0:27 offset1:24\n\t"
            "ds_read2_b32 %4, %10 offset0:21 offset1:18\n\t"
            "ds_read2_b32 %5, %10 offset0:15 offset1:12\n\t"
            "ds_read2_b32 %6, %10 offset0:9 offset1:6\n\t"
            "ds_read2_b32 %7, %10 offset0:3 offset1:0\n\t"
            "ds_read2_b32 %8, %10 offset0:43 offset1:44\n\t"
            "ds_read2_b32 %9, %10 offset0:46 offset1:47\n\t"
            "s_waitcnt lgkmcnt(0)"
            : "=&v"(p0), "=&v"(p1), "=&v"(p2), "=&v"(p3), "=&v"(p4),
              "=&v"(p5), "=&v"(p6), "=&v"(p7), "=&v"(q0), "=&v"(q1)
            : "v"(addr));
        const v2f f0  = UP(p0.x), f1  = UP(p0.y), f2  = UP(p1.x), f3  = UP(p1.y);
        const v2f f4  = UP(p2.x), f5  = UP(p2.y), f6  = UP(p3.x), f7  = UP(p3.y);
        const v2f f8  = UP(p4.x), f9  = UP(p4.y), f10 = UP(p5.x), f11 = UP(p5.y);
        const v2f f12 = UP(p6.x), f13 = UP(p6.y), f14 = UP(p7.x), f15 = UP(p7.y);
        const v2f e0 = UP(q0.x), e1 = UP(q0.y);   // offs 43, 44
        const v2f e2 = UP(q1.x), e3 = UP(q1.y);   // offs 46, 47
        const v2f s = (((f0 + f1) + (f2 + f3)) + ((f4 + f5) + (f6 + f7))) +
                      (((f8 + f9) + (f10 + f11)) + ((f12 + f13) + (f14 + f15)));
        v2f r;
        r.x = __builtin_amdgcn_rcpf(s.x);
        r.y = __builtin_amdgcn_rcpf(s.y);
        acc1[0]  = pfma(f0,  r, acc1[0]);   acc1[1]  = pfma(f1,  r, acc1[1]);
        acc1[2]  = pfma(f2,  r, acc1[2]);   acc1[3]  = pfma(f3,  r, acc1[3]);
        acc1[4]  = pfma(f4,  r, acc1[4]);   acc1[5]  = pfma(f5,  r, acc1[5]);
        acc1[6]  = pfma(f6,  r, acc1[6]);   acc1[7]  = pfma(f7,  r, acc1[7]);
        acc1[8]  = pfma(f8,  r, acc1[8]);   acc1[9]  = pfma(f9,  r, acc1[9]);
        acc1[10] = pfma(f10, r, acc1[10]);  acc1[11] = pfma(f11, r, acc1[11]);
        acc1[12] = pfma(f12, r, acc1[12]);  acc1[13] = pfma(f13, r, acc1[13]);
        acc1[14] = pfma(f14, r, acc1[14]);  acc1[15] = pfma(f15, r, acc1[15]);
        const v2f s2 = ((e0 + e1) + (e2 + e3)) + f0;
        v2f r2;
        r2.x = __builtin_amdgcn_rcpf(s2.x);
        r2.y = __builtin_amdgcn_rcpf(s2.y);
        acc2[0] = pfma(e3, r2, acc2[0]);
        acc2[1] = pfma(e2, r2, acc2[1]);
        acc2[2] = pfma(f0, r2, acc2[2]);
        acc2[3] = pfma(e1, r2, acc2[3]);
        acc2[4] = pfma(e0, r2, acc2[4]);
        addr += kRow * 4;
      }
    }
    __syncthreads();

    // ---- phase C (R9-identical): disjoint slot dump
    if (t < kWc1) {
      float* __restrict__ R = &P[g * kRStr + t * kAcc];
      #pragma unroll
      for (int k = 0; k < kD0; ++k) R[k] = acc1[k].x + acc1[k].y;
      #pragma unroll
      for (int j = 0; j < kD1; ++j) R[kD0 + j] = acc2[j].x + acc2[j].y;
    }
    __syncthreads();

    // ---- phase D (R9-identical): combine + coalesced writes
    for (int i = tid; i < kN1 + kN2; i += kThreads) {
      if (i < kN1) {
        const int d   = i / kWc1;
        const int col = i % kWc1;
        const int o   = col * kAcc + d;
        const float v = P[o] + P[kRStr + o] + P[2 * kRStr + o];
        out[((b * kD0 + d) * kH + h) * kWc1 + col] =
            (3.0f * (float)d) * (4.0f + v);              // C/D0 = 4
      } else {
        const int i2  = i - kN1;
        const int j   = i2 / kWc2;
        const int col = i2 % kWc2;
        const int o   = col * kAcc + kD0 + j;
        const float v = P[o] + P[kRStr + o] + P[2 * kRStr + o];
        out[kOut1 + ((b * kD1 + j) * kH + h) * kWc2 + col] =
            (float)(j - 2) * (64.0f / 5.0f + v);         // C/D1 = 12.8
      }
    }
    __syncthreads();   // D(row) reads of P done before next row's C writes
  }
}

extern "C" void kernel_launch(void* const* d_in, const int* in_sizes, int n_in,
                              void* d_out, int out_size, void* d_ws, size_t ws_size,
                              hipStream_t stream) {
  const float* feat_r = (const float*)d_in[1];  // feats_l contributes exactly C/D
  float* out = (float*)d_out;
  anynet_disp_kernel<<<dim3(kB * kH / kRowsPerBlk), dim3(kThreads), 0, stream>>>(
      feat_r, out);
}

// Round 15
// 14.518 us; speedup vs baseline: 3.2247x; 3.2247x over previous
//
#include <hip/hip_runtime.h>

namespace {
constexpr int kB   = 2;
constexpr int kC   = 64;
constexpr int kH   = 128;
constexpr int kW   = 240;
constexpr int kD0  = 16;          // disps 0,3,...,45
constexpr int kD1  = 5;           // disps -2,-1,0,1,2
constexpr int kWc1 = 285;
constexpr int kWc2 = 242;
constexpr int kPad = 48;          // left pad (>= max disp 45)
constexpr int kRow = 336;         // dwords per cpair row (48 pad |240 data |48 pad)
constexpr int kCP  = 32;          // channel pairs (64 channels)
constexpr int kGroups   = 3;      // cpair-parallel groups {11,11,10}
constexpr int kGThreads = 320;
constexpr int kThreads  = kGroups * kGThreads;  // 960 = 15 waves
constexpr int kAcc  = kD0 + kD1;  // 21
constexpr int kRStr = kWc1 * kAcc;             // 5985 floats per partial slot
constexpr int kOut1 = kB * kD0 * kH * kWc1;
constexpr int kN1   = kD0 * kWc1;              // 4560
constexpr int kN2   = kD1 * kWc2;              // 1210
typedef unsigned int v2u __attribute__((ext_vector_type(2)));
typedef _Float16 h2 __attribute__((ext_vector_type(2)));

__device__ __forceinline__ unsigned int pkh(float lo, float hi) {
  return __builtin_bit_cast(unsigned int, __builtin_amdgcn_cvt_pkrtz(lo, hi));
}
__device__ __forceinline__ h2 H2(unsigned int u) {
  return __builtin_bit_cast(h2, u);
}
// v_dot2_f32_f16: a.x*b.x + a.y*b.y + c  (f32 accumulate)
__device__ __forceinline__ float dot2(h2 a, h2 b, float c) {
  return __builtin_amdgcn_fdot2(a, b, c, false);
}
}

__global__ __launch_bounds__(kThreads)
void anynet_disp_kernel(const float* __restrict__ fr, float* __restrict__ out) {
  __shared__ unsigned int E[kCP * kRow];  // f16x2 exp(feat_r): ch 2cp | 2cp+1
  __shared__ float P[kGroups * kRStr];    // dedicated partial slots
  const int bh  = blockIdx.x;             // 0..255
  const int b   = bh >> 7;
  const int h   = bh & 127;
  const int tid = threadIdx.x;

  // ---- phase A (MLP): issue all 4 global loads FIRST, pads under latency
  const float* fr_b = fr + (size_t)b * kC * kH * kW + (size_t)h * kW;
  const int i0 = tid, i1 = tid + kThreads;        // both < 1920
  const int cp0 = i0 / 60, xq0 = i0 % 60;
  const int cp1 = i1 / 60, xq1 = i1 % 60;
  const float4 a0 = *reinterpret_cast<const float4*>(
      fr_b + (size_t)(2 * cp0) * (kH * kW) + 4 * xq0);
  const float4 b0 = *reinterpret_cast<const float4*>(
      fr_b + (size_t)(2 * cp0 + 1) * (kH * kW) + 4 * xq0);
  const float4 a1 = *reinterpret_cast<const float4*>(
      fr_b + (size_t)(2 * cp1) * (kH * kW) + 4 * xq1);
  const float4 b1 = *reinterpret_cast<const float4*>(
      fr_b + (size_t)(2 * cp1 + 1) * (kH * kW) + 4 * xq1);
  if (tid < kCP * 24) {
    const int cp = tid / 24, q = tid % 24;
    const int j4 = (q < 12) ? q : q + 60;         // uint4 [0,12) and [72,84)
    const uint4 ones = {0x3C003C00u, 0x3C003C00u, 0x3C003C00u, 0x3C003C00u};
    *reinterpret_cast<uint4*>(&E[cp * kRow + 4 * j4]) = ones;   // f16(1.0)x2
  }
  {
    uint4 w0;
    w0.x = pkh(__expf(a0.x), __expf(b0.x));
    w0.y = pkh(__expf(a0.y), __expf(b0.y));
    w0.z = pkh(__expf(a0.z), __expf(b0.z));
    w0.w = pkh(__expf(a0.w), __expf(b0.w));
    *reinterpret_cast<uint4*>(&E[cp0 * kRow + kPad + 4 * xq0]) = w0;
    uint4 w1;
    w1.x = pkh(__expf(a1.x), __expf(b1.x));
    w1.y = pkh(__expf(a1.y), __expf(b1.y));
    w1.z = pkh(__expf(a1.z), __expf(b1.z));
    w1.w = pkh(__expf(a1.w), __expf(b1.w));
    *reinterpret_cast<uint4*>(&E[cp1 * kRow + kPad + 4 * xq1]) = w1;
  }
  __syncthreads();

  // ---- phase B: proven 10x ds_read2_b32 tap fetch; f16 packed math.
  // Denominators via v_pk_add_f16 trees (per-channel); accumulate via
  // v_dot2_f32_f16 (both channels fused into one scalar f32 acc).
  const int g = tid / kGThreads;      // 0..2
  const int t = tid % kGThreads;
  float acc1[kD0] = {};
  float acc2[kD1] = {};
  if (t < kWc1) {
    const int cbeg = (g == 0) ? 0 : (g == 1 ? 11 : 22);
    const int clen = (g < 2) ? 11 : 10;
    unsigned int addr = (unsigned int)(uintptr_t)(const void*)&E[cbeg * kRow + t + 3];
    for (int cc = 0; cc < clen; ++cc) {
      v2u p0, p1, p2, p3, p4, p5, p6, p7, q0, q1;
      asm volatile(
          "ds_read2_b32 %0, %10 offset0:45 offset1:42\n\t"
          "ds_read2_b32 %1, %10 offset0:39 offset1:36\n\t"
          "ds_read2_b32 %2, %10 offset0:33 offset1:30\n\t"
          "ds_read2_b32 %3, %10 offset0:27 offset1:24\n\t"
          "ds_read2_b32 %4, %10 offset0:21 offset1:18\n\t"
          "ds_read2_b32 %5, %10 offset0:15 offset1:12\n\t"
          "ds_read2_b32 %6, %10 offset0:9 offset1:6\n\t"
          "ds_read2_b32 %7, %10 offset0:3 offset1:0\n\t"
          "ds_read2_b32 %8, %10 offset0:43 offset1:44\n\t"
          "ds_read2_b32 %9, %10 offset0:46 offset1:47\n\t"
          "s_waitcnt lgkmcnt(0)"
          : "=&v"(p0), "=&v"(p1), "=&v"(p2), "=&v"(p3), "=&v"(p4),
            "=&v"(p5), "=&v"(p6), "=&v"(p7), "=&v"(q0), "=&v"(q1)
          : "v"(addr));
      // D0 taps k=0..15 at offsets 45-3k: t0=p0.x, t1=p0.y, ..., t15=p7.y
      const h2 t0  = H2(p0.x), t1  = H2(p0.y), t2  = H2(p1.x), t3  = H2(p1.y);
      const h2 t4  = H2(p2.x), t5  = H2(p2.y), t6  = H2(p3.x), t7  = H2(p3.y);
      const h2 t8  = H2(p4.x), t9  = H2(p4.y), t10 = H2(p5.x), t11 = H2(p5.y);
      const h2 t12 = H2(p6.x), t13 = H2(p6.y), t14 = H2(p7.x), t15 = H2(p7.y);
      const h2 u0 = H2(q0.x), u1 = H2(q0.y);   // offsets 43, 44
      const h2 u2 = H2(q1.x), u3 = H2(q1.y);   // offsets 46, 47
      // D0 denominator, both channels: 15 v_pk_add_f16
      const h2 s = (((t0 + t1) + (t2 + t3)) + ((t4 + t5) + (t6 + t7))) +
                   (((t8 + t9) + (t10 + t11)) + ((t12 + t13) + (t14 + t15)));
      const float rlo = __builtin_amdgcn_rcpf((float)s.x);
      const float rhi = __builtin_amdgcn_rcpf((float)s.y);
      const h2 rp = H2(pkh(rlo, rhi));
      acc1[0]  = dot2(t0,  rp, acc1[0]);   acc1[1]  = dot2(t1,  rp, acc1[1]);
      acc1[2]  = dot2(t2,  rp, acc1[2]);   acc1[3]  = dot2(t3,  rp, acc1[3]);
      acc1[4]  = dot2(t4,  rp, acc1[4]);   acc1[5]  = dot2(t5,  rp, acc1[5]);
      acc1[6]  = dot2(t6,  rp, acc1[6]);   acc1[7]  = dot2(t7,  rp, acc1[7]);
      acc1[8]  = dot2(t8,  rp, acc1[8]);   acc1[9]  = dot2(t9,  rp, acc1[9]);
      acc1[10] = dot2(t10, rp, acc1[10]);  acc1[11] = dot2(t11, rp, acc1[11]);
      acc1[12] = dot2(t12, rp, acc1[12]);  acc1[13] = dot2(t13, rp, acc1[13]);
      acc1[14] = dot2(t14, rp, acc1[14]);  acc1[15] = dot2(t15, rp, acc1[15]);
      // D1 denominator: taps 43,44,45,46,47 = u0,u1,t0,u2,u3
      const h2 s2 = ((u0 + u1) + (u2 + u3)) + t0;
      const float r2lo = __builtin_amdgcn_rcpf((float)s2.x);
      const float r2hi = __builtin_amdgcn_rcpf((float)s2.y);
      const h2 r2p = H2(pkh(r2lo, r2hi));
      acc2[0] = dot2(u3, r2p, acc2[0]);   // offset 47
      acc2[1] = dot2(u2, r2p, acc2[1]);   // offset 46
      acc2[2] = dot2(t0, r2p, acc2[2]);   // offset 45
      acc2[3] = dot2(u1, r2p, acc2[3]);   // offset 44
      acc2[4] = dot2(u0, r2p, acc2[4]);   // offset 43
      addr += kRow * 4;
    }
  }
  __syncthreads();

  // ---- phase C: each group writes its OWN slot (disjoint, proven)
  if (t < kWc1) {
    float* __restrict__ R = &P[g * kRStr + t * kAcc];  // stride 21: conflict-free
    #pragma unroll
    for (int k = 0; k < kD0; ++k) R[k] = acc1[k];
    #pragma unroll
    for (int j = 0; j < kD1; ++j) R[kD0 + j] = acc2[j];
  }
  __syncthreads();

  // ---- phase D: combine 3 slots, coalesced writes (proven)
  for (int i = tid; i < kN1 + kN2; i += kThreads) {
    if (i < kN1) {
      const int d   = i / kWc1;
      const int col = i % kWc1;
      const int o   = col * kAcc + d;
      const float v = P[o] + P[kRStr + o] + P[2 * kRStr + o];
      out[((b * kD0 + d) * kH + h) * kWc1 + col] =
          (3.0f * (float)d) * (4.0f + v);              // C/D0 = 4
    } else {
      const int i2  = i - kN1;
      const int j   = i2 / kWc2;
      const int col = i2 % kWc2;
      const int o   = col * kAcc + kD0 + j;
      const float v = P[o] + P[kRStr + o] + P[2 * kRStr + o];
      out[kOut1 + ((b * kD1 + j) * kH + h) * kWc2 + col] =
          (float)(j - 2) * (64.0f / 5.0f + v);         // C/D1 = 12.8
    }
  }
}

extern "C" void kernel_launch(void* const* d_in, const int* in_sizes, int n_in,
                              void* d_out, int out_size, void* d_ws, size_t ws_size,
                              hipStream_t stream) {
  const float* feat_r = (const float*)d_in[1];  // feats_l contributes exactly C/D
  float* out = (float*)d_out;
  anynet_disp_kernel<<<dim3(kB * kH), dim3(kThreads), 0, stream>>>(feat_r, out);
}